// Round 7
// baseline (199.931 us; speedup 1.0000x reference)
//
#include <hip/hip_runtime.h>
#include <cstdint>

typedef unsigned short u16;
typedef unsigned int u32;
typedef float f32x4 __attribute__((ext_vector_type(4)));
typedef __bf16 bf16x8 __attribute__((ext_vector_type(8)));
typedef __bf16 bf16x4 __attribute__((ext_vector_type(4)));
typedef u16 u16x8 __attribute__((ext_vector_type(8)));

#define B_ 2
#define S_ 2048
#define NX_ 1024
#define NH_ 16
#define HD_ 64
#define T3_ 3072
#define M_ 4096          // B_*S_ tokens
#define SCL 0.18033688011112042f   // 0.125 * log2(e)

__device__ __forceinline__ u16 bfbits(float f) {
    __bf16 h = (__bf16)f;            // native cvt (RNE), pairs to v_cvt_pk_bf16_f32
    return __builtin_bit_cast(u16, h);
}

__device__ __forceinline__ void gload_lds16(const void* g, void* l) {
    auto gp = reinterpret_cast<const __attribute__((address_space(1))) u32*>(
        reinterpret_cast<uintptr_t>(g));
    auto lp = reinterpret_cast<__attribute__((address_space(3))) u32*>(
        reinterpret_cast<uintptr_t>(l));
    __builtin_amdgcn_global_load_lds(gp, lp, 16, 0, 0);
}

// ---------------- convert f32 -> bf16, vectorized ----------------
__global__ __launch_bounds__(256) void cvt_bf16_kernel(const float* __restrict__ X,
                                                       u16* __restrict__ Y) {
    int i = (blockIdx.x * 256 + threadIdx.x) * 4;
    float4 v = *reinterpret_cast<const float4*>(X + i);
    bf16x4 o;
    o[0] = (__bf16)v.x; o[1] = (__bf16)v.y; o[2] = (__bf16)v.z; o[3] = (__bf16)v.w;
    *reinterpret_cast<bf16x4*>(Y + i) = o;
}

// ---------------- transpose + convert: W[K][N] f32 -> WT[N][K] bf16 ----------------
__global__ __launch_bounds__(256) void transpose_cvt_kernel(const float* __restrict__ W,
                                                            u16* __restrict__ WT,
                                                            int K, int N) {
    __shared__ float tile[32][33];
    int nbx = N >> 5;
    int nb = (blockIdx.x % nbx) << 5;
    int kb = (blockIdx.x / nbx) << 5;
    int tx = threadIdx.x & 31, ty = threadIdx.x >> 5;
#pragma unroll
    for (int i = 0; i < 32; i += 8)
        tile[ty + i][tx] = W[(size_t)(kb + ty + i) * N + nb + tx];
    __syncthreads();
#pragma unroll
    for (int i = 0; i < 32; i += 8)
        WT[(size_t)(nb + ty + i) * K + kb + tx] = bfbits(tile[tx][ty + i]);
}

// ---------------- bf16 GEMM: C[M][N] = A[M][K] * Bt[N][K]^T + bias ----------------
// If Vt!=null, columns >= vcol0 are written transposed per-head: Vt[g=b*16+h][d][s].
#define BM 128
#define BN 128
#define BK 64
__global__ __launch_bounds__(256) void gemm_bt_kernel(const u16* __restrict__ A,
                                                      const u16* __restrict__ Bt,
                                                      const float* __restrict__ bias,
                                                      u16* __restrict__ Cb,
                                                      float* __restrict__ Cf,
                                                      u16* __restrict__ Vt,
                                                      int vcol0,
                                                      int M, int N, int K) {
    __shared__ u16 a_lds[BM * BK];
    __shared__ u16 b_lds[BN * BK];
    int nbn = N / BN;
    int nwg = gridDim.x;
    int orig = blockIdx.x;
    int wg = (orig & 7) * (nwg >> 3) + (orig >> 3);   // XCD-contiguous chunks
    int bm = wg / nbn, bn = wg % nbn;
    int t = threadIdx.x;
    int w = t >> 6, l = t & 63, lg = l >> 4, lr = l & 15;
    int wr = w >> 1, wc = w & 1;
    const u16* Abase = A + (size_t)bm * BM * K;
    const u16* Bbase = Bt + (size_t)bn * BN * K;

    f32x4 zero4 = {0.f, 0.f, 0.f, 0.f};
    f32x4 acc[4][4];
#pragma unroll
    for (int m = 0; m < 4; ++m)
#pragma unroll
        for (int n = 0; n < 4; ++n) acc[m][n] = zero4;

    int nkt = K / BK;
    for (int kt = 0; kt < nkt; ++kt) {
#pragma unroll
        for (int it = 0; it < 4; ++it) {
            int idx = it * 256 + t;          // 16B chunk id
            int row = idx >> 3, ck = idx & 7;
            int ldsoff = (it * 256 + w * 64) * 8;   // wave-uniform, u16 units
            gload_lds16(Abase + (size_t)row * K + kt * BK + ck * 8, a_lds + ldsoff);
            gload_lds16(Bbase + (size_t)row * K + kt * BK + ck * 8, b_lds + ldsoff);
        }
        __syncthreads();
#pragma unroll
        for (int ks = 0; ks < 2; ++ks) {
            bf16x8 af[4], bf[4];
#pragma unroll
            for (int m = 0; m < 4; ++m)
                af[m] = *reinterpret_cast<const bf16x8*>(
                    a_lds + (wr * 64 + m * 16 + lr) * BK + ks * 32 + lg * 8);
#pragma unroll
            for (int n = 0; n < 4; ++n)
                bf[n] = *reinterpret_cast<const bf16x8*>(
                    b_lds + (wc * 64 + n * 16 + lr) * BK + ks * 32 + lg * 8);
#pragma unroll
            for (int m = 0; m < 4; ++m)
#pragma unroll
                for (int n = 0; n < 4; ++n)
                    acc[m][n] = __builtin_amdgcn_mfma_f32_16x16x32_bf16(
                        af[m], bf[n], acc[m][n], 0, 0, 0);
        }
        __syncthreads();
    }
#pragma unroll
    for (int n = 0; n < 4; ++n) {
        int col0 = bn * BN + wc * 64 + n * 16;
        int col = col0 + lr;
        float bv = bias[col];
        bool isv = (Vt != nullptr) && (col0 >= vcol0);
#pragma unroll
        for (int m = 0; m < 4; ++m) {
            int row0 = bm * BM + wr * 64 + m * 16 + lg * 4;
            if (isv) {
                int nv = col - vcol0, hh = nv >> 6, dd = nv & 63;
                int bb = row0 >> 11, ss = row0 & 2047;
                bf16x4 pk;
#pragma unroll
                for (int r = 0; r < 4; ++r) pk[r] = (__bf16)(acc[m][n][r] + bv);
                *reinterpret_cast<bf16x4*>(
                    Vt + (((size_t)(bb * 16 + hh) * 64 + dd) << 11) + ss) = pk;
            } else {
#pragma unroll
                for (int r = 0; r < 4; ++r) {
                    float v = acc[m][n][r] + bv;
                    if (Cf) Cf[(size_t)(row0 + r) * N + col] = v;
                    else    Cb[(size_t)(row0 + r) * N + col] = bfbits(v);
                }
            }
        }
    }
}

// ---------------- flash attention, barrier-free: K/V fragments direct from L2 ----------------
// 1024 blocks (4 waves x 16 q-rows = q-tile 64); zero __syncthreads. K from qkv,
// V from pre-transposed Vt — per-head 512 KB is L2-resident (g pinned to one XCD).
// P goes through wave-private swizzled LDS (8 KB total). Balanced qt map.
__global__ __launch_bounds__(256, 4) void attn_kernel(const u16* __restrict__ qkv,
                                                      const u16* __restrict__ Vt,
                                                      u16* __restrict__ outa) {
    __shared__ u16 p_lds[4096];      // [q 64][k 64], chunk16-swizzled ^ (row&7)

    int bid = blockIdx.x;
    int g = bid & 31;                // same g -> same XCD (stride 32 ≡ 0 mod 8)
    int j = bid >> 5;                // 0..31
    int j0 = j & 7, kk = j >> 3;
    int qt = (kk == 0) ? j0 : (kk == 1) ? (31 - j0) : (kk == 2) ? (8 + j0) : (23 - j0);
    int b = g >> 4, h = g & 15;
    int t = threadIdx.x, w = t >> 6, l = t & 63, lg = l >> 4, lr = l & 15;
    const u16* base = qkv + (size_t)b * S_ * T3_;
    const u16* vbase = Vt + (size_t)g * 64 * S_;
    int prow = w * 16 + lr;          // local P row (wave-private slab)
    int qb = qt * 64;
    int qrow = qb + w * 16 + lr;     // this lane's q (column of S^T)

    // per-lane fragment base pointers
    const u16* kptr = base + (size_t)lr * T3_ + NX_ + h * 64 + lg * 8;  // + (kb+kn*16)*T3 + ks*32
    const u16* vptr = vbase + (size_t)lr * S_ + lg * 8;                 // + dc*16*S + kb + ks*32

    f32x4 zero4 = {0.f, 0.f, 0.f, 0.f};

    bf16x8 qf[2];
#pragma unroll
    for (int ks = 0; ks < 2; ++ks)
        qf[ks] = *reinterpret_cast<const bf16x8*>(
            base + (size_t)qrow * T3_ + h * 64 + ks * 32 + lg * 8);

    f32x4 oacc[4];
#pragma unroll
    for (int dc = 0; dc < 4; ++dc) oacc[dc] = zero4;
    float mrun = -1e30f, lrun = 0.f;
    int nkt = qt + 1;

    for (int kt = 0; kt < nkt; ++kt) {
        int kb = kt * 64;

        // K fragments direct from L2 (A-operand: row=lr -> kv, k-dim = d)
        bf16x8 kf[2][4];
#pragma unroll
        for (int ks = 0; ks < 2; ++ks)
#pragma unroll
            for (int kn = 0; kn < 4; ++kn)
                kf[ks][kn] = *reinterpret_cast<const bf16x8*>(
                    kptr + (size_t)(kb + kn * 16) * T3_ + ks * 32);

        // S^T = K Q^T : lane holds S[k = kn*16+lg*4+r][q = qrow]
        f32x4 sacc[4];
#pragma unroll
        for (int kn = 0; kn < 4; ++kn) sacc[kn] = zero4;
        __builtin_amdgcn_s_setprio(1);
#pragma unroll
        for (int ks = 0; ks < 2; ++ks)
#pragma unroll
            for (int kn = 0; kn < 4; ++kn)
                sacc[kn] = __builtin_amdgcn_mfma_f32_16x16x32_bf16(
                    kf[ks][kn], qf[ks], sacc[kn], 0, 0, 0);
        __builtin_amdgcn_s_setprio(0);

        // V fragments issued now; softmax VALU below hides their latency
        bf16x8 vf[2][4];
#pragma unroll
        for (int ks = 0; ks < 2; ++ks)
#pragma unroll
            for (int dc = 0; dc < 4; ++dc)
                vf[ks][dc] = *reinterpret_cast<const bf16x8*>(
                    vptr + (size_t)(dc * 16) * S_ + kb + ks * 32);

        if (kt == qt) {   // diagonal tile: causal mask (k_local > q_local)
            int qloc = w * 16 + lr;
#pragma unroll
            for (int kn = 0; kn < 4; ++kn)
#pragma unroll
                for (int r = 0; r < 4; ++r)
                    if (kn * 16 + lg * 4 + r > qloc) sacc[kn][r] = -1e30f;
        }

        // in-register online softmax (16 in-lane + 2 shfl across lg groups)
        float mx = -1e30f;
#pragma unroll
        for (int kn = 0; kn < 4; ++kn) {
            float a0 = fmaxf(sacc[kn][0], sacc[kn][1]);
            float a1 = fmaxf(sacc[kn][2], sacc[kn][3]);
            mx = fmaxf(mx, fmaxf(a0, a1));
        }
        mx = fmaxf(mx, __shfl_xor(mx, 16));
        mx = fmaxf(mx, __shfl_xor(mx, 32));

        bool noresc = __all(mx <= mrun + 8.0f);   // defer-max: P bounded by 2^(8*SCL)=2.7
        float mnew = noresc ? mrun : fmaxf(mrun, mx);

        float rs = 0.f;
#pragma unroll
        for (int kn = 0; kn < 4; ++kn)
#pragma unroll
            for (int r = 0; r < 4; ++r) {
                float pv = exp2f((sacc[kn][r] - mnew) * SCL);
                sacc[kn][r] = pv;
                rs += pv;
            }
        rs += __shfl_xor(rs, 16);
        rs += __shfl_xor(rs, 32);

        if (noresc) {
            lrun += rs;
        } else {
            float fsc = exp2f((mrun - mnew) * SCL);
            mrun = mnew;
            lrun = lrun * fsc + rs;
            float f0 = __shfl(fsc, lg * 4 + 0);
            float f1 = __shfl(fsc, lg * 4 + 1);
            float f2 = __shfl(fsc, lg * 4 + 2);
            float f3 = __shfl(fsc, lg * 4 + 3);
#pragma unroll
            for (int dc = 0; dc < 4; ++dc) {
                oacc[dc][0] *= f0; oacc[dc][1] *= f1;
                oacc[dc][2] *= f2; oacc[dc][3] *= f3;
            }
        }

        // P -> LDS, packed 8B writes, swizzled (wave-private slab: no barrier needed)
#pragma unroll
        for (int kn = 0; kn < 4; ++kn) {
            bf16x4 pb;
            pb[0] = (__bf16)sacc[kn][0]; pb[1] = (__bf16)sacc[kn][1];
            pb[2] = (__bf16)sacc[kn][2]; pb[3] = (__bf16)sacc[kn][3];
            int byteoff = prow * 128 + (((2 * kn + (lg >> 1)) ^ (prow & 7)) * 16) + (lg & 1) * 8;
            *reinterpret_cast<bf16x4*>(reinterpret_cast<char*>(p_lds) + byteoff) = pb;
        }

        // O += P V  (A = P rows from LDS, B = V fragments in registers)
        __builtin_amdgcn_s_setprio(1);
#pragma unroll
        for (int ks = 0; ks < 2; ++ks) {
            bf16x8 pf = *reinterpret_cast<const bf16x8*>(
                reinterpret_cast<char*>(p_lds) + prow * 128 + (((ks * 4 + lg) ^ (prow & 7)) * 16));
#pragma unroll
            for (int dc = 0; dc < 4; ++dc)
                oacc[dc] = __builtin_amdgcn_mfma_f32_16x16x32_bf16(
                    pf, vf[ks][dc], oacc[dc], 0, 0, 0);
        }
        __builtin_amdgcn_s_setprio(0);
    }

    // epilogue: O /= l ; store bf16 [token][h*64+d]
    float inv = 1.f / lrun;
    float i0 = __shfl(inv, lg * 4 + 0);
    float i1 = __shfl(inv, lg * 4 + 1);
    float i2 = __shfl(inv, lg * 4 + 2);
    float i3 = __shfl(inv, lg * 4 + 3);
    u16* ob = outa + (size_t)b * S_ * NX_;
#pragma unroll
    for (int r = 0; r < 4; ++r) {
        float ir = (r == 0) ? i0 : (r == 1) ? i1 : (r == 2) ? i2 : i3;
        int row = qb + w * 16 + lg * 4 + r;
#pragma unroll
        for (int dc = 0; dc < 4; ++dc)
            ob[(size_t)row * NX_ + h * 64 + dc * 16 + lr] = bfbits(oacc[dc][r] * ir);
    }
}

extern "C" void kernel_launch(void* const* d_in, const int* in_sizes, int n_in,
                              void* d_out, int out_size, void* d_ws, size_t ws_size,
                              hipStream_t stream) {
    const float* x        = (const float*)d_in[0];
    const float* c_attn_w = (const float*)d_in[1];
    const float* c_attn_b = (const float*)d_in[2];
    const float* c_proj_w = (const float*)d_in[3];
    const float* c_proj_b = (const float*)d_in[4];
    float* out = (float*)d_out;

    u16* xb     = (u16*)d_ws;                         // [4096][1024] bf16  (8 MB)
    u16* wqkvT  = xb + (size_t)M_ * NX_;              // [3072][1024] bf16  (6 MB)
    u16* wprojT = wqkvT + (size_t)T3_ * NX_;          // [1024][1024] bf16  (2 MB)
    u16* qkv    = wprojT + (size_t)NX_ * NX_;         // [4096][3072] bf16  (24 MB; V part unused)
    u16* attno  = xb;                                 // reuse xb after GEMM1 (8 MB)
    u16* Vtp    = (u16*)d_out;                        // scratch: Vt 8 MB inside 16 MB out;
                                                      // fully overwritten by GEMM2 at the end

    // 1) x -> bf16
    cvt_bf16_kernel<<<(M_ * NX_) / 1024, 256, 0, stream>>>(x, xb);
    // 2) weights -> transposed bf16
    transpose_cvt_kernel<<<(T3_ / 32) * (NX_ / 32), 256, 0, stream>>>(c_attn_w, wqkvT, NX_, T3_);
    transpose_cvt_kernel<<<(NX_ / 32) * (NX_ / 32), 256, 0, stream>>>(c_proj_w, wprojT, NX_, NX_);
    // 3) qkv = x @ c_attn_w + b (bf16 out); V-part written transposed to Vtp
    gemm_bt_kernel<<<(M_ / BM) * (T3_ / BN), 256, 0, stream>>>(
        xb, wqkvT, c_attn_b, qkv, nullptr, Vtp, 2 * NX_, M_, T3_, NX_);
    // 4) attention (barrier-free, direct-L2 fragments, 1024 blocks)
    attn_kernel<<<1024, 256, 0, stream>>>(qkv, Vtp, attno);
    // 5) out = attn @ c_proj_w + b  (f32 out)
    gemm_bt_kernel<<<(M_ / BM) * (NX_ / BN), 256, 0, stream>>>(
        attno, wprojT, c_proj_b, nullptr, out, nullptr, 0, M_, NX_, NX_);
}

// Round 8
// 133.288 us; speedup vs baseline: 1.5000x; 1.5000x over previous
//
#include <hip/hip_runtime.h>
#include <cstdint>

typedef unsigned short u16;
typedef unsigned int u32;
typedef float f32x4 __attribute__((ext_vector_type(4)));
typedef float f32x16 __attribute__((ext_vector_type(16)));
typedef __bf16 bf16x8 __attribute__((ext_vector_type(8)));
typedef __bf16 bf16x4 __attribute__((ext_vector_type(4)));
typedef __bf16 bf16x2 __attribute__((ext_vector_type(2)));
typedef u16 u16x8 __attribute__((ext_vector_type(8)));
typedef u32 u32x4 __attribute__((ext_vector_type(4)));

#define B_ 2
#define S_ 2048
#define NX_ 1024
#define NH_ 16
#define HD_ 64
#define T3_ 3072
#define M_ 4096          // B_*S_ tokens
#define SCL 0.18033688011112042f   // 0.125 * log2(e)

__device__ __forceinline__ u16 bfbits(float f) {
    __bf16 h = (__bf16)f;
    return __builtin_bit_cast(u16, h);
}
__device__ __forceinline__ u32 pk2(float a, float b) {
    bf16x2 t; t[0] = (__bf16)a; t[1] = (__bf16)b;   // -> v_cvt_pk_bf16_f32
    return __builtin_bit_cast(u32, t);
}

__device__ __forceinline__ void gload_lds16(const void* g, void* l) {
    auto gp = reinterpret_cast<const __attribute__((address_space(1))) u32*>(
        reinterpret_cast<uintptr_t>(g));
    auto lp = reinterpret_cast<__attribute__((address_space(3))) u32*>(
        reinterpret_cast<uintptr_t>(l));
    __builtin_amdgcn_global_load_lds(gp, lp, 16, 0, 0);
}

// ---------------- convert f32 -> bf16, vectorized ----------------
__global__ __launch_bounds__(256) void cvt_bf16_kernel(const float* __restrict__ X,
                                                       u16* __restrict__ Y) {
    int i = (blockIdx.x * 256 + threadIdx.x) * 4;
    float4 v = *reinterpret_cast<const float4*>(X + i);
    bf16x4 o;
    o[0] = (__bf16)v.x; o[1] = (__bf16)v.y; o[2] = (__bf16)v.z; o[3] = (__bf16)v.w;
    *reinterpret_cast<bf16x4*>(Y + i) = o;
}

// ---------------- transpose + convert: W[K][N] f32 -> WT[N][K] bf16 ----------------
__global__ __launch_bounds__(256) void transpose_cvt_kernel(const float* __restrict__ W,
                                                            u16* __restrict__ WT,
                                                            int K, int N) {
    __shared__ float tile[32][33];
    int nbx = N >> 5;
    int nb = (blockIdx.x % nbx) << 5;
    int kb = (blockIdx.x / nbx) << 5;
    int tx = threadIdx.x & 31, ty = threadIdx.x >> 5;
#pragma unroll
    for (int i = 0; i < 32; i += 8)
        tile[ty + i][tx] = W[(size_t)(kb + ty + i) * N + nb + tx];
    __syncthreads();
#pragma unroll
    for (int i = 0; i < 32; i += 8)
        WT[(size_t)(nb + ty + i) * K + kb + tx] = bfbits(tile[tx][ty + i]);
}

// ---------------- bf16 GEMM: C[M][N] = A[M][K] * Bt[N][K]^T + bias ----------------
// If Vt!=null, columns >= vcol0 are written transposed per-head: Vt[g=b*16+h][d][s].
#define BM 128
#define BN 128
#define BK 64
__global__ __launch_bounds__(256) void gemm_bt_kernel(const u16* __restrict__ A,
                                                      const u16* __restrict__ Bt,
                                                      const float* __restrict__ bias,
                                                      u16* __restrict__ Cb,
                                                      float* __restrict__ Cf,
                                                      u16* __restrict__ Vt,
                                                      int vcol0,
                                                      int M, int N, int K) {
    __shared__ u16 a_lds[BM * BK];
    __shared__ u16 b_lds[BN * BK];
    int nbn = N / BN;
    int nwg = gridDim.x;
    int orig = blockIdx.x;
    int wg = (orig & 7) * (nwg >> 3) + (orig >> 3);   // XCD-contiguous chunks
    int bm = wg / nbn, bn = wg % nbn;
    int t = threadIdx.x;
    int w = t >> 6, l = t & 63, lg = l >> 4, lr = l & 15;
    int wr = w >> 1, wc = w & 1;
    const u16* Abase = A + (size_t)bm * BM * K;
    const u16* Bbase = Bt + (size_t)bn * BN * K;

    f32x4 zero4 = {0.f, 0.f, 0.f, 0.f};
    f32x4 acc[4][4];
#pragma unroll
    for (int m = 0; m < 4; ++m)
#pragma unroll
        for (int n = 0; n < 4; ++n) acc[m][n] = zero4;

    int nkt = K / BK;
    for (int kt = 0; kt < nkt; ++kt) {
#pragma unroll
        for (int it = 0; it < 4; ++it) {
            int idx = it * 256 + t;          // 16B chunk id
            int row = idx >> 3, ck = idx & 7;
            int ldsoff = (it * 256 + w * 64) * 8;   // wave-uniform, u16 units
            gload_lds16(Abase + (size_t)row * K + kt * BK + ck * 8, a_lds + ldsoff);
            gload_lds16(Bbase + (size_t)row * K + kt * BK + ck * 8, b_lds + ldsoff);
        }
        __syncthreads();
#pragma unroll
        for (int ks = 0; ks < 2; ++ks) {
            bf16x8 af[4], bf[4];
#pragma unroll
            for (int m = 0; m < 4; ++m)
                af[m] = *reinterpret_cast<const bf16x8*>(
                    a_lds + (wr * 64 + m * 16 + lr) * BK + ks * 32 + lg * 8);
#pragma unroll
            for (int n = 0; n < 4; ++n)
                bf[n] = *reinterpret_cast<const bf16x8*>(
                    b_lds + (wc * 64 + n * 16 + lr) * BK + ks * 32 + lg * 8);
#pragma unroll
            for (int m = 0; m < 4; ++m)
#pragma unroll
                for (int n = 0; n < 4; ++n)
                    acc[m][n] = __builtin_amdgcn_mfma_f32_16x16x32_bf16(
                        af[m], bf[n], acc[m][n], 0, 0, 0);
        }
        __syncthreads();
    }
#pragma unroll
    for (int n = 0; n < 4; ++n) {
        int col0 = bn * BN + wc * 64 + n * 16;
        int col = col0 + lr;
        float bv = bias[col];
        bool isv = (Vt != nullptr) && (col0 >= vcol0);
#pragma unroll
        for (int m = 0; m < 4; ++m) {
            int row0 = bm * BM + wr * 64 + m * 16 + lg * 4;
            if (isv) {
                int nv = col - vcol0, hh = nv >> 6, dd = nv & 63;
                int bb = row0 >> 11, ss = row0 & 2047;
                bf16x4 pk;
#pragma unroll
                for (int r = 0; r < 4; ++r) pk[r] = (__bf16)(acc[m][n][r] + bv);
                *reinterpret_cast<bf16x4*>(
                    Vt + (((size_t)(bb * 16 + hh) * 64 + dd) << 11) + ss) = pk;
            } else {
#pragma unroll
                for (int r = 0; r < 4; ++r) {
                    float v = acc[m][n][r] + bv;
                    if (Cf) Cf[(size_t)(row0 + r) * N + col] = v;
                    else    Cb[(size_t)(row0 + r) * N + col] = bfbits(v);
                }
            }
        }
    }
}

// ---------------- flash attention: 32x32 MFMA, in-register P, kv-split 2 ----------------
// Block = 4 waves x 32 q-rows = q-tile 128; kv-tile 64; grid 1024 (32 g x 16 qt x 2 s).
// S^T = mfma32(K, Q): lane holds S[kv][q = qb+w*32+(l&31)]. Writes UNNORMALIZED partials
// + (m,l); merge_kernel combines the two kv-halves.
__global__ __launch_bounds__(256) void attn_kernel(const u16* __restrict__ qkv,
                                                   const u16* __restrict__ Vt,
                                                   u16* __restrict__ part0,
                                                   u16* __restrict__ part1,
                                                   float* __restrict__ mlb) {
    __shared__ u16 k_lds[2][4096];   // [kv 64][d 64], 16B-chunk swizzled ^ (row&7)
    __shared__ u16 v_lds[2][4096];   // [d 64][kv 64], 16B-chunk swizzled ^ (row&7)

    int bid = blockIdx.x;
    int g = bid & 31;                // same g -> same XCD (stride 32 ≡ 0 mod 8)
    int j = bid >> 5;                // 0..31
    int qt = 15 - (j >> 1);          // longest q-tiles dispatched first
    int s = j & 1;                   // kv half
    int b = g >> 4, h = g & 15;
    int t = threadIdx.x, w = t >> 6, l = t & 63;
    int c31 = l & 31, hi = l >> 5;
    const u16* base = qkv + (size_t)b * S_ * T3_;
    const u16* vbase = Vt + (size_t)g * 64 * S_;
    int srow = w * 8 + (l >> 3);     // staging row (it adds 32)
    int qb = qt * 128 + w * 32;      // wave's q base
    int q = qb + c31;                // this lane's q (column of S^T)

    int tw = 2 * qt + (w >> 1);      // wave's last needed kv-tile (diagonal)
    int H = qt + 1;                  // split point
    int k0 = s ? H : 0;
    int k1b = s ? (2 * qt + 2) : H;  // block-uniform staged range [k0, k1b)

    auto stage = [&](int kt2, int bs) {
        int kb2 = kt2 * 64;
#pragma unroll
        for (int it = 0; it < 2; ++it) {
            int row = it * 32 + srow;
            int ckg = (l & 7) ^ (row & 7);       // pre-swizzled global chunk
            gload_lds16(base + (size_t)(kb2 + row) * T3_ + NX_ + h * 64 + ckg * 8,
                        &k_lds[bs][(it * 32 + w * 8) * 64]);
            gload_lds16(vbase + (size_t)row * S_ + kb2 + ckg * 8,
                        &v_lds[bs][(it * 32 + w * 8) * 64]);
        }
    };

    // Q fragments: B-operand, col = q = l&31, k(d) = ks*16 + hi*8 + i
    bf16x8 qf[4];
#pragma unroll
    for (int ks = 0; ks < 4; ++ks)
        qf[ks] = *reinterpret_cast<const bf16x8*>(
            base + (size_t)q * T3_ + h * 64 + ks * 16 + hi * 8);

    f32x16 oacc[2];
#pragma unroll
    for (int dc = 0; dc < 2; ++dc)
#pragma unroll
        for (int r = 0; r < 16; ++r) oacc[dc][r] = 0.f;
    float mrun = -1e30f, lrun = 0.f;

    stage(k0, 0);
    __syncthreads();

    for (int kt = k0; kt < k1b; ++kt) {
        int cur = (kt - k0) & 1;
        if (kt + 1 < k1b) stage(kt + 1, cur ^ 1);

        if (kt <= tw) {
            int kb = kt * 64;
            // S^T = K Q^T via 32x32x16
            f32x16 sacc[2];
#pragma unroll
            for (int kn = 0; kn < 2; ++kn)
#pragma unroll
                for (int r = 0; r < 16; ++r) sacc[kn][r] = 0.f;
            __builtin_amdgcn_s_setprio(1);
#pragma unroll
            for (int ks = 0; ks < 4; ++ks) {
#pragma unroll
                for (int kn = 0; kn < 2; ++kn) {
                    int row = kn * 32 + c31;
                    int ck = (ks * 2 + hi) ^ (row & 7);
                    bf16x8 kf = *reinterpret_cast<const bf16x8*>(
                        &k_lds[cur][row * 64 + ck * 8]);
                    sacc[kn] = __builtin_amdgcn_mfma_f32_32x32x16_bf16(
                        kf, qf[ks], sacc[kn], 0, 0, 0);
                }
            }
            __builtin_amdgcn_s_setprio(0);

            if (kt == tw) {   // diagonal tile: mask kv > q
#pragma unroll
                for (int kn = 0; kn < 2; ++kn)
#pragma unroll
                    for (int r = 0; r < 16; ++r) {
                        int kv = kb + kn * 32 + (r & 3) + 8 * (r >> 2) + 4 * hi;
                        if (kv > q) sacc[kn][r] = -1e30f;
                    }
            }

            // online softmax: in-lane over 32 + one cross-half exchange
            float mx = -1e30f;
#pragma unroll
            for (int kn = 0; kn < 2; ++kn)
#pragma unroll
                for (int r = 0; r < 16; ++r) mx = fmaxf(mx, sacc[kn][r]);
            mx = fmaxf(mx, __shfl_xor(mx, 32));

            bool noresc = __all(mx <= mrun + 8.0f);   // defer-max: P <= 2.72
            float mnew = noresc ? mrun : fmaxf(mrun, mx);

            float rs = 0.f;
#pragma unroll
            for (int kn = 0; kn < 2; ++kn)
#pragma unroll
                for (int r = 0; r < 16; ++r) {
                    float pv = exp2f((sacc[kn][r] - mnew) * SCL);
                    sacc[kn][r] = pv;
                    rs += pv;
                }
            rs += __shfl_xor(rs, 32);

            if (noresc) {
                lrun += rs;
            } else {
                float fsc = exp2f((mrun - mnew) * SCL);
                mrun = mnew;
                lrun = lrun * fsc + rs;
#pragma unroll
                for (int r = 0; r < 16; ++r) {
                    int cr = (r & 3) + 8 * (r >> 2) + 4 * hi;   // oacc row (q-local)
                    float f = __shfl(fsc, cr);                  // lane cr owns q-local cr
                    oacc[0][r] *= f; oacc[1][r] *= f;
                }
            }

            // P -> PV A-fragments in registers (no LDS)
            __builtin_amdgcn_s_setprio(1);
#pragma unroll
            for (int kn = 0; kn < 2; ++kn) {
                u32 a0 = pk2(sacc[kn][0],  sacc[kn][1]),  a1 = pk2(sacc[kn][2],  sacc[kn][3]);
                u32 b0 = pk2(sacc[kn][4],  sacc[kn][5]),  b1 = pk2(sacc[kn][6],  sacc[kn][7]);
                u32 c0 = pk2(sacc[kn][8],  sacc[kn][9]),  c1 = pk2(sacc[kn][10], sacc[kn][11]);
                u32 d0 = pk2(sacc[kn][12], sacc[kn][13]), d1 = pk2(sacc[kn][14], sacc[kn][15]);
                u32 pa0 = __shfl_xor(a0, 32), pa1 = __shfl_xor(a1, 32);
                u32 pb0 = __shfl_xor(b0, 32), pb1 = __shfl_xor(b1, 32);
                u32 pc0 = __shfl_xor(c0, 32), pc1 = __shfl_xor(c1, 32);
                u32 pd0 = __shfl_xor(d0, 32), pd1 = __shfl_xor(d1, 32);
                u32x4 f0, f1;   // A-frags for k-slices kn*2, kn*2+1
                f0[0] = hi ? pb0 : a0;  f0[1] = hi ? pb1 : a1;
                f0[2] = hi ? b0 : pa0;  f0[3] = hi ? b1 : pa1;
                f1[0] = hi ? pd0 : c0;  f1[1] = hi ? pd1 : c1;
                f1[2] = hi ? d0 : pc0;  f1[3] = hi ? d1 : pc1;
                bf16x8 pf0 = __builtin_bit_cast(bf16x8, f0);
                bf16x8 pf1 = __builtin_bit_cast(bf16x8, f1);
                // O += P V for these two k-slices
#pragma unroll
                for (int dc = 0; dc < 2; ++dc) {
                    int d = dc * 32 + c31;
                    int ck0 = ((kn * 2 + 0) * 2 + hi) ^ (d & 7);
                    int ck1 = ((kn * 2 + 1) * 2 + hi) ^ (d & 7);
                    bf16x8 vf0 = *reinterpret_cast<const bf16x8*>(
                        &v_lds[cur][d * 64 + ck0 * 8]);
                    oacc[dc] = __builtin_amdgcn_mfma_f32_32x32x16_bf16(
                        pf0, vf0, oacc[dc], 0, 0, 0);
                    bf16x8 vf1 = *reinterpret_cast<const bf16x8*>(
                        &v_lds[cur][d * 64 + ck1 * 8]);
                    oacc[dc] = __builtin_amdgcn_mfma_f32_32x32x16_bf16(
                        pf1, vf1, oacc[dc], 0, 0, 0);
                }
            }
            __builtin_amdgcn_s_setprio(0);
        }
        __syncthreads();   // single barrier/tile: buffer reads done before restage
    }

    // partial epilogue: store UNNORMALIZED Osum (bf16) + (m,l) f32
    u16* pb = (s ? part1 : part0) + (size_t)b * S_ * NX_;
#pragma unroll
    for (int r = 0; r < 16; ++r) {
        int cr = (r & 3) + 8 * (r >> 2) + 4 * hi;
        int row = qb + cr;
#pragma unroll
        for (int dc = 0; dc < 2; ++dc)
            pb[(size_t)row * NX_ + h * 64 + dc * 32 + c31] = bfbits(oacc[dc][r]);
    }
    if (hi == 0) {   // lane owns state for q = qb + c31
        float* f = mlb + (size_t)(b * S_ + q) * (T3_ / 2) + NX_ + h * 4 + s * 2;
        f[0] = mrun; f[1] = lrun;
    }
}

// ---------------- merge: out = (O0*e0 + O1*e1) / (l0*e0 + l1*e1), in place ----------------
__global__ __launch_bounds__(256) void merge_kernel(u16* __restrict__ part0,
                                                    const u16* __restrict__ part1,
                                                    const float* __restrict__ mlb) {
    int idx = blockIdx.x * 256 + threadIdx.x;   // (tok, h)
    int tok = idx >> 4, h = idx & 15;
    const float* f = mlb + (size_t)tok * (T3_ / 2) + NX_ + h * 4;
    float m0 = f[0], l0 = f[1], m1 = f[2], l1 = f[3];
    float M = fmaxf(m0, m1);
    float e0 = exp2f((m0 - M) * SCL), e1 = exp2f((m1 - M) * SCL);
    float inv = 1.f / (l0 * e0 + l1 * e1);
    float a = e0 * inv, c = e1 * inv;
    u16* p0 = part0 + (size_t)tok * NX_ + h * 64;
    const u16* p1 = part1 + (size_t)tok * NX_ + h * 64;
#pragma unroll
    for (int i = 0; i < 8; ++i) {
        bf16x8 v0 = *reinterpret_cast<const bf16x8*>(p0 + i * 8);
        bf16x8 v1 = *reinterpret_cast<const bf16x8*>(p1 + i * 8);
        bf16x8 o;
#pragma unroll
        for (int k = 0; k < 8; ++k)
            o[k] = (__bf16)((float)v0[k] * a + (float)v1[k] * c);
        *reinterpret_cast<bf16x8*>(p0 + i * 8) = o;
    }
}

extern "C" void kernel_launch(void* const* d_in, const int* in_sizes, int n_in,
                              void* d_out, int out_size, void* d_ws, size_t ws_size,
                              hipStream_t stream) {
    const float* x        = (const float*)d_in[0];
    const float* c_attn_w = (const float*)d_in[1];
    const float* c_attn_b = (const float*)d_in[2];
    const float* c_proj_w = (const float*)d_in[3];
    const float* c_proj_b = (const float*)d_in[4];
    float* out = (float*)d_out;

    u16* xb     = (u16*)d_ws;                         // [4096][1024] bf16  (8 MB)
    u16* wqkvT  = xb + (size_t)M_ * NX_;              // [3072][1024] bf16  (6 MB)
    u16* wprojT = wqkvT + (size_t)T3_ * NX_;          // [1024][1024] bf16  (2 MB)
    u16* qkv    = wprojT + (size_t)NX_ * NX_;         // [4096][3072] bf16  (24 MB;
                                                      //  V-third reused for (m,l) scratch)
    u16* attno  = xb;                                 // partial s0 / final attn out (8 MB)
    u16* Vtp    = (u16*)d_out;                        // Vt 8 MB in lower half of out
    u16* part1  = Vtp + (size_t)32 * 64 * S_;         // partial s1, upper 8 MB of out
    float* mlb  = (float*)qkv;                        // (m,l) live in qkv V-third

    // 1) x -> bf16
    cvt_bf16_kernel<<<(M_ * NX_) / 1024, 256, 0, stream>>>(x, xb);
    // 2) weights -> transposed bf16
    transpose_cvt_kernel<<<(T3_ / 32) * (NX_ / 32), 256, 0, stream>>>(c_attn_w, wqkvT, NX_, T3_);
    transpose_cvt_kernel<<<(NX_ / 32) * (NX_ / 32), 256, 0, stream>>>(c_proj_w, wprojT, NX_, NX_);
    // 3) qkv = x @ c_attn_w + b (bf16 out); V-part written transposed to Vtp
    gemm_bt_kernel<<<(M_ / BM) * (T3_ / BN), 256, 0, stream>>>(
        xb, wqkvT, c_attn_b, qkv, nullptr, Vtp, 2 * NX_, M_, T3_, NX_);
    // 4) attention: 32-row waves, kv-split 2 (1024 blocks)
    attn_kernel<<<1024, 256, 0, stream>>>(qkv, Vtp, attno, part1, mlb);
    // 4b) merge partials (in place into attno)
    merge_kernel<<<(M_ * NH_) / 256, 256, 0, stream>>>(attno, part1, mlb);
    // 5) out = attn @ c_proj_w + b  (f32 out)
    gemm_bt_kernel<<<(M_ / BM) * (NX_ / BN), 256, 0, stream>>>(
        attno, wprojT, c_proj_b, nullptr, out, nullptr, 0, M_, NX_, NX_);
}

// Round 9
// 129.280 us; speedup vs baseline: 1.5465x; 1.0310x over previous
//
#include <hip/hip_runtime.h>
#include <cstdint>

typedef unsigned short u16;
typedef unsigned int u32;
typedef float f32x4 __attribute__((ext_vector_type(4)));
typedef __bf16 bf16x8 __attribute__((ext_vector_type(8)));
typedef __bf16 bf16x4 __attribute__((ext_vector_type(4)));
typedef u16 u16x8 __attribute__((ext_vector_type(8)));

#define B_ 2
#define S_ 2048
#define NX_ 1024
#define NH_ 16
#define HD_ 64
#define T3_ 3072
#define M_ 4096          // B_*S_ tokens
#define SCL 0.18033688011112042f   // 0.125 * log2(e)

__device__ __forceinline__ u16 bfbits(float f) {
    __bf16 h = (__bf16)f;            // native cvt (RNE), pairs to v_cvt_pk_bf16_f32
    return __builtin_bit_cast(u16, h);
}

__device__ __forceinline__ void gload_lds16(const void* g, void* l) {
    auto gp = reinterpret_cast<const __attribute__((address_space(1))) u32*>(
        reinterpret_cast<uintptr_t>(g));
    auto lp = reinterpret_cast<__attribute__((address_space(3))) u32*>(
        reinterpret_cast<uintptr_t>(l));
    __builtin_amdgcn_global_load_lds(gp, lp, 16, 0, 0);
}

// ---------------- convert f32 -> bf16, vectorized ----------------
__global__ __launch_bounds__(256) void cvt_bf16_kernel(const float* __restrict__ X,
                                                       u16* __restrict__ Y) {
    int i = (blockIdx.x * 256 + threadIdx.x) * 4;
    float4 v = *reinterpret_cast<const float4*>(X + i);
    bf16x4 o;
    o[0] = (__bf16)v.x; o[1] = (__bf16)v.y; o[2] = (__bf16)v.z; o[3] = (__bf16)v.w;
    *reinterpret_cast<bf16x4*>(Y + i) = o;
}

// ---------------- transpose + convert: W[K][N] f32 -> WT[N][K] bf16 ----------------
__global__ __launch_bounds__(256) void transpose_cvt_kernel(const float* __restrict__ W,
                                                            u16* __restrict__ WT,
                                                            int K, int N) {
    __shared__ float tile[32][33];
    int nbx = N >> 5;
    int nb = (blockIdx.x % nbx) << 5;
    int kb = (blockIdx.x / nbx) << 5;
    int tx = threadIdx.x & 31, ty = threadIdx.x >> 5;
#pragma unroll
    for (int i = 0; i < 32; i += 8)
        tile[ty + i][tx] = W[(size_t)(kb + ty + i) * N + nb + tx];
    __syncthreads();
#pragma unroll
    for (int i = 0; i < 32; i += 8)
        WT[(size_t)(nb + ty + i) * K + kb + tx] = bfbits(tile[tx][ty + i]);
}

// ---------------- 128^2 bf16 GEMM (proven m97-style) — used for GEMM2 ----------------
#define BM 128
#define BN 128
#define BK 64
__global__ __launch_bounds__(256) void gemm_bt_kernel(const u16* __restrict__ A,
                                                      const u16* __restrict__ Bt,
                                                      const float* __restrict__ bias,
                                                      u16* __restrict__ Cb,
                                                      float* __restrict__ Cf,
                                                      int M, int N, int K) {
    __shared__ u16 a_lds[BM * BK];
    __shared__ u16 b_lds[BN * BK];
    int nbn = N / BN;
    int nwg = gridDim.x;
    int orig = blockIdx.x;
    int wg = (orig & 7) * (nwg >> 3) + (orig >> 3);   // XCD-contiguous chunks
    int bm = wg / nbn, bn = wg % nbn;
    int t = threadIdx.x;
    int w = t >> 6, l = t & 63, lg = l >> 4, lr = l & 15;
    int wr = w >> 1, wc = w & 1;
    const u16* Abase = A + (size_t)bm * BM * K;
    const u16* Bbase = Bt + (size_t)bn * BN * K;

    f32x4 zero4 = {0.f, 0.f, 0.f, 0.f};
    f32x4 acc[4][4];
#pragma unroll
    for (int m = 0; m < 4; ++m)
#pragma unroll
        for (int n = 0; n < 4; ++n) acc[m][n] = zero4;

    int nkt = K / BK;
    for (int kt = 0; kt < nkt; ++kt) {
#pragma unroll
        for (int it = 0; it < 4; ++it) {
            int idx = it * 256 + t;          // 16B chunk id
            int row = idx >> 3, ck = idx & 7;
            int ldsoff = (it * 256 + w * 64) * 8;   // wave-uniform, u16 units
            gload_lds16(Abase + (size_t)row * K + kt * BK + ck * 8, a_lds + ldsoff);
            gload_lds16(Bbase + (size_t)row * K + kt * BK + ck * 8, b_lds + ldsoff);
        }
        __syncthreads();
#pragma unroll
        for (int ks = 0; ks < 2; ++ks) {
            bf16x8 af[4], bf[4];
#pragma unroll
            for (int m = 0; m < 4; ++m)
                af[m] = *reinterpret_cast<const bf16x8*>(
                    a_lds + (wr * 64 + m * 16 + lr) * BK + ks * 32 + lg * 8);
#pragma unroll
            for (int n = 0; n < 4; ++n)
                bf[n] = *reinterpret_cast<const bf16x8*>(
                    b_lds + (wc * 64 + n * 16 + lr) * BK + ks * 32 + lg * 8);
#pragma unroll
            for (int m = 0; m < 4; ++m)
#pragma unroll
                for (int n = 0; n < 4; ++n)
                    acc[m][n] = __builtin_amdgcn_mfma_f32_16x16x32_bf16(
                        af[m], bf[n], acc[m][n], 0, 0, 0);
        }
        __syncthreads();
    }
#pragma unroll
    for (int n = 0; n < 4; ++n) {
        int col = bn * BN + wc * 64 + n * 16 + lr;
        float bv = bias[col];
#pragma unroll
        for (int m = 0; m < 4; ++m) {
            int row0 = bm * BM + wr * 64 + m * 16 + lg * 4;
#pragma unroll
            for (int r = 0; r < 4; ++r) {
                float v = acc[m][n][r] + bv;
                if (Cf) Cf[(size_t)(row0 + r) * N + col] = v;
                else    Cb[(size_t)(row0 + r) * N + col] = bfbits(v);
            }
        }
    }
}

// ---------------- 256^2 double-buffered prefetch GEMM — GEMM1 (qkv) ----------------
// 512 thr (8 waves 2Mx4N), BK=64, LDS 128KB dbuf, chunk-XOR swizzle (T2),
// prefetch-next-then-compute with ONE __syncthreads per K-tile (T3 minimum recipe:
// the barrier's vmcnt(0) drains loads issued BEFORE ~24 ds_read + 64 MFMA -> amortized).
// Columns >= vcol0 written transposed per-head: Vt[g=b*16+h][d][s].
__global__ __launch_bounds__(512, 2) void gemm256_bt_kernel(const u16* __restrict__ A,
                                                            const u16* __restrict__ Bt,
                                                            const float* __restrict__ bias,
                                                            u16* __restrict__ Cb,
                                                            u16* __restrict__ Vt,
                                                            int vcol0,
                                                            int M, int N, int K) {
    __shared__ u16 a_lds[2][256 * 64];
    __shared__ u16 b_lds[2][256 * 64];
    int nbn = N / 256;
    int nwg = gridDim.x;             // divisible by 8
    int orig = blockIdx.x;
    int wg = (orig & 7) * (nwg >> 3) + (orig >> 3);   // bijective XCD swizzle
    int bm = wg / nbn, bn = wg % nbn;
    int t = threadIdx.x;
    int wid = t >> 6, l = t & 63, lg = l >> 4, lr = l & 15;
    int wr = wid >> 2, wc = wid & 3;         // 2 x 4 wave grid; wave tile 128x64
    const u16* Abase = A + (size_t)bm * 256 * K;
    const u16* Bbase = Bt + (size_t)bn * 256 * K;

    f32x4 acc[8][4] = {};

    // stage tile kt into buffer bs: linear LDS dest (wave-uniform base + lane*16),
    // inverse-swizzled global source chunk (m201 both-sides pattern).
    auto stage = [&](int kt, int bs) {
#pragma unroll
        for (int gld = 0; gld < 4; ++gld) {
            int idx = gld * 512 + wid * 64 + l;      // 0..2047 = 256 rows x 8 chunks
            int row = idx >> 3, ck = idx & 7;
            int cds = ck ^ (row & 7);                // data chunk stored in this slot
            int ubase = (gld * 512 + wid * 64) * 8;  // u16 units, wave-uniform
            gload_lds16(Abase + (size_t)row * K + kt * 64 + cds * 8, &a_lds[bs][ubase]);
            gload_lds16(Bbase + (size_t)row * K + kt * 64 + cds * 8, &b_lds[bs][ubase]);
        }
    };

    stage(0, 0);
    __syncthreads();

    int nkt = K / 64;
    for (int kt = 0; kt < nkt; ++kt) {
        int cur = kt & 1;
        if (kt + 1 < nkt) stage(kt + 1, cur ^ 1);   // prefetch into other buffer

        // compute tile kt from buf[cur]: 4 quadrant phases (regs stay bounded)
#pragma unroll
        for (int ph = 0; ph < 4; ++ph) {
            int mh = ph >> 1, nh = ph & 1;
            bf16x8 af[4][2], bf[2][2];
#pragma unroll
            for (int mm = 0; mm < 4; ++mm) {
                int row = wr * 128 + (mh * 4 + mm) * 16 + lr;
#pragma unroll
                for (int ks = 0; ks < 2; ++ks) {
                    int ck = (ks * 4 + lg) ^ (row & 7);
                    af[mm][ks] = *reinterpret_cast<const bf16x8*>(
                        &a_lds[cur][row * 64 + ck * 8]);
                }
            }
#pragma unroll
            for (int nn = 0; nn < 2; ++nn) {
                int row = wc * 64 + (nh * 2 + nn) * 16 + lr;
#pragma unroll
                for (int ks = 0; ks < 2; ++ks) {
                    int ck = (ks * 4 + lg) ^ (row & 7);
                    bf[nn][ks] = *reinterpret_cast<const bf16x8*>(
                        &b_lds[cur][row * 64 + ck * 8]);
                }
            }
            __builtin_amdgcn_s_setprio(1);
#pragma unroll
            for (int ks = 0; ks < 2; ++ks)
#pragma unroll
                for (int mm = 0; mm < 4; ++mm)
#pragma unroll
                    for (int nn = 0; nn < 2; ++nn)
                        acc[mh * 4 + mm][nh * 2 + nn] =
                            __builtin_amdgcn_mfma_f32_16x16x32_bf16(
                                af[mm][ks], bf[nn][ks],
                                acc[mh * 4 + mm][nh * 2 + nn], 0, 0, 0);
            __builtin_amdgcn_s_setprio(0);
        }
        __syncthreads();   // one barrier/tile: drains my prefetch (amortized) +
                           // guarantees all waves done reading buf[cur]
    }

    // epilogue
#pragma unroll
    for (int n = 0; n < 4; ++n) {
        int col0 = bn * 256 + wc * 64 + n * 16;
        int col = col0 + lr;
        float bv = bias[col];
        bool isv = (Vt != nullptr) && (col0 >= vcol0);
#pragma unroll
        for (int m = 0; m < 8; ++m) {
            int row0 = bm * 256 + wr * 128 + m * 16 + lg * 4;
            if (isv) {
                int nv = col - vcol0, hh = nv >> 6, dd = nv & 63;
                int bb = row0 >> 11, ss = row0 & 2047;
                bf16x4 pk;
#pragma unroll
                for (int r = 0; r < 4; ++r) pk[r] = (__bf16)(acc[m][n][r] + bv);
                *reinterpret_cast<bf16x4*>(
                    Vt + (((size_t)(bb * 16 + hh) * 64 + dd) << 11) + ss) = pk;
            } else {
#pragma unroll
                for (int r = 0; r < 4; ++r)
                    Cb[(size_t)(row0 + r) * N + col] = bfbits(acc[m][n][r] + bv);
            }
        }
    }
}

// ---------------- flash attention (R4, proven 57 us): swapped-QK^T 16x16 ----------------
// One q-tile (64 rows) per block, 1024 blocks, balanced qt map, single barrier/tile.
__global__ __launch_bounds__(256) void attn_kernel(const u16* __restrict__ qkv,
                                                   const u16* __restrict__ Vt,
                                                   u16* __restrict__ outa) {
    __shared__ u16 k_lds[2][4096];   // [k 64][d 64], chunk16-swizzled ^ (row&7)
    __shared__ u16 v_lds[2][4096];   // [d 64][k 64], chunk16-swizzled ^ (row&7)
    __shared__ u16 p_lds[4096];      // [q 64][k 64], chunk16-swizzled ^ (row&7)

    int bid = blockIdx.x;
    int g = bid & 31;                // same g -> same XCD (stride 32 ≡ 0 mod 8)
    int j = bid >> 5;                // 0..31
    int j0 = j & 7, kk = j >> 3;
    int qt = (kk == 0) ? j0 : (kk == 1) ? (31 - j0) : (kk == 2) ? (8 + j0) : (23 - j0);
    int b = g >> 4, h = g & 15;
    int t = threadIdx.x, w = t >> 6, l = t & 63, lg = l >> 4, lr = l & 15;
    const u16* base = qkv + (size_t)b * S_ * T3_;
    const u16* vbase = Vt + (size_t)g * 64 * S_;
    int prow = w * 16 + lr;          // local P row (wave-private slab)
    int srow = w * 8 + (l >> 3);     // staging row (it adds 32)
    int qb = qt * 64;
    int qrow = qb + w * 16 + lr;     // this lane's q (column of S^T)

    auto stage = [&](int kt2, int bs) {
        int kb2 = kt2 * 64;
#pragma unroll
        for (int it = 0; it < 2; ++it) {
            int row = it * 32 + srow;
            int ckg = (l & 7) ^ (row & 7);       // pre-swizzled global chunk
            gload_lds16(base + (size_t)(kb2 + row) * T3_ + NX_ + h * 64 + ckg * 8,
                        &k_lds[bs][(it * 32 + w * 8) * 64]);
            gload_lds16(vbase + (size_t)row * S_ + kb2 + ckg * 8,
                        &v_lds[bs][(it * 32 + w * 8) * 64]);
        }
    };

    f32x4 zero4 = {0.f, 0.f, 0.f, 0.f};

    bf16x8 qf[2];
#pragma unroll
    for (int ks = 0; ks < 2; ++ks)
        qf[ks] = *reinterpret_cast<const bf16x8*>(
            base + (size_t)qrow * T3_ + h * 64 + ks * 32 + lg * 8);

    f32x4 oacc[4];
#pragma unroll
    for (int dc = 0; dc < 4; ++dc) oacc[dc] = zero4;
    float mrun = -1e30f, lrun = 0.f;
    int nkt = qt + 1;

    stage(0, 0);
    __syncthreads();

    for (int kt = 0; kt < nkt; ++kt) {
        int cur = kt & 1;
        if (kt + 1 < nkt) stage(kt + 1, cur ^ 1);   // issue early; drains at end barrier

        // S^T = K Q^T : lane holds S[k = kn*16+lg*4+r][q = qrow]
        f32x4 sacc[4];
#pragma unroll
        for (int kn = 0; kn < 4; ++kn) sacc[kn] = zero4;
        __builtin_amdgcn_s_setprio(1);
#pragma unroll
        for (int ks = 0; ks < 2; ++ks) {
#pragma unroll
            for (int kn = 0; kn < 4; ++kn) {
                bf16x8 kf = *reinterpret_cast<const bf16x8*>(
                    &k_lds[cur][(kn * 16 + lr) * 64 + (((ks * 4 + lg) ^ (lr & 7)) * 8)]);
                sacc[kn] = __builtin_amdgcn_mfma_f32_16x16x32_bf16(
                    kf, qf[ks], sacc[kn], 0, 0, 0);
            }
        }
        __builtin_amdgcn_s_setprio(0);

        if (kt == qt) {   // diagonal tile: causal mask (k_local > q_local)
            int qloc = w * 16 + lr;
#pragma unroll
            for (int kn = 0; kn < 4; ++kn)
#pragma unroll
                for (int r = 0; r < 4; ++r)
                    if (kn * 16 + lg * 4 + r > qloc) sacc[kn][r] = -1e30f;
        }

        // in-register online softmax (16 in-lane + 2 shfl across lg groups)
        float mx = -1e30f;
#pragma unroll
        for (int kn = 0; kn < 4; ++kn) {
            float a0 = fmaxf(sacc[kn][0], sacc[kn][1]);
            float a1 = fmaxf(sacc[kn][2], sacc[kn][3]);
            mx = fmaxf(mx, fmaxf(a0, a1));
        }
        mx = fmaxf(mx, __shfl_xor(mx, 16));
        mx = fmaxf(mx, __shfl_xor(mx, 32));

        bool noresc = __all(mx <= mrun + 8.0f);   // defer-max: P bounded by 2^(8*SCL)=2.7
        float mnew = noresc ? mrun : fmaxf(mrun, mx);

        float rs = 0.f;
#pragma unroll
        for (int kn = 0; kn < 4; ++kn)
#pragma unroll
            for (int r = 0; r < 4; ++r) {
                float pv = exp2f((sacc[kn][r] - mnew) * SCL);
                sacc[kn][r] = pv;
                rs += pv;
            }
        rs += __shfl_xor(rs, 16);
        rs += __shfl_xor(rs, 32);

        if (noresc) {
            lrun += rs;
        } else {
            float fsc = exp2f((mrun - mnew) * SCL);
            mrun = mnew;
            lrun = lrun * fsc + rs;
            float f0 = __shfl(fsc, lg * 4 + 0);
            float f1 = __shfl(fsc, lg * 4 + 1);
            float f2 = __shfl(fsc, lg * 4 + 2);
            float f3 = __shfl(fsc, lg * 4 + 3);
#pragma unroll
            for (int dc = 0; dc < 4; ++dc) {
                oacc[dc][0] *= f0; oacc[dc][1] *= f1;
                oacc[dc][2] *= f2; oacc[dc][3] *= f3;
            }
        }

        // P -> LDS, packed 8B writes, swizzled (wave-private slab: no barrier needed)
#pragma unroll
        for (int kn = 0; kn < 4; ++kn) {
            bf16x4 pb;
            pb[0] = (__bf16)sacc[kn][0]; pb[1] = (__bf16)sacc[kn][1];
            pb[2] = (__bf16)sacc[kn][2]; pb[3] = (__bf16)sacc[kn][3];
            int byteoff = prow * 128 + (((2 * kn + (lg >> 1)) ^ (prow & 7)) * 16) + (lg & 1) * 8;
            *reinterpret_cast<bf16x4*>(reinterpret_cast<char*>(p_lds) + byteoff) = pb;
        }

        // O += P V  (A = P rows from LDS, B = Vt rows)
        __builtin_amdgcn_s_setprio(1);
#pragma unroll
        for (int ks = 0; ks < 2; ++ks) {
            bf16x8 pf = *reinterpret_cast<const bf16x8*>(
                reinterpret_cast<char*>(p_lds) + prow * 128 + (((ks * 4 + lg) ^ (prow & 7)) * 16));
#pragma unroll
            for (int dc = 0; dc < 4; ++dc) {
                bf16x8 vf = *reinterpret_cast<const bf16x8*>(
                    &v_lds[cur][(dc * 16 + lr) * 64 + (((ks * 4 + lg) ^ (lr & 7)) * 8)]);
                oacc[dc] = __builtin_amdgcn_mfma_f32_16x16x32_bf16(
                    pf, vf, oacc[dc], 0, 0, 0);
            }
        }
        __builtin_amdgcn_s_setprio(0);
        __syncthreads();   // single barrier/tile: k/v_lds[cur] reads done before reuse
    }

    // epilogue: O /= l ; store bf16 [token][h*64+d]
    float inv = 1.f / lrun;
    float i0 = __shfl(inv, lg * 4 + 0);
    float i1 = __shfl(inv, lg * 4 + 1);
    float i2 = __shfl(inv, lg * 4 + 2);
    float i3 = __shfl(inv, lg * 4 + 3);
    u16* ob = outa + (size_t)b * S_ * NX_;
#pragma unroll
    for (int r = 0; r < 4; ++r) {
        float ir = (r == 0) ? i0 : (r == 1) ? i1 : (r == 2) ? i2 : i3;
        int row = qb + w * 16 + lg * 4 + r;
#pragma unroll
        for (int dc = 0; dc < 4; ++dc)
            ob[(size_t)row * NX_ + h * 64 + dc * 16 + lr] = bfbits(oacc[dc][r] * ir);
    }
}

extern "C" void kernel_launch(void* const* d_in, const int* in_sizes, int n_in,
                              void* d_out, int out_size, void* d_ws, size_t ws_size,
                              hipStream_t stream) {
    const float* x        = (const float*)d_in[0];
    const float* c_attn_w = (const float*)d_in[1];
    const float* c_attn_b = (const float*)d_in[2];
    const float* c_proj_w = (const float*)d_in[3];
    const float* c_proj_b = (const float*)d_in[4];
    float* out = (float*)d_out;

    u16* xb     = (u16*)d_ws;                         // [4096][1024] bf16  (8 MB)
    u16* wqkvT  = xb + (size_t)M_ * NX_;              // [3072][1024] bf16  (6 MB)
    u16* wprojT = wqkvT + (size_t)T3_ * NX_;          // [1024][1024] bf16  (2 MB)
    u16* qkv    = wprojT + (size_t)NX_ * NX_;         // [4096][3072] bf16  (24 MB; V part unused)
    u16* attno  = xb;                                 // reuse xb after GEMM1 (8 MB)
    u16* Vtp    = (u16*)d_out;                        // scratch: Vt 8 MB inside 16 MB out;
                                                      // fully overwritten by GEMM2 at the end

    // 1) x -> bf16
    cvt_bf16_kernel<<<(M_ * NX_) / 1024, 256, 0, stream>>>(x, xb);
    // 2) weights -> transposed bf16
    transpose_cvt_kernel<<<(T3_ / 32) * (NX_ / 32), 256, 0, stream>>>(c_attn_w, wqkvT, NX_, T3_);
    transpose_cvt_kernel<<<(NX_ / 32) * (NX_ / 32), 256, 0, stream>>>(c_proj_w, wprojT, NX_, NX_);
    // 3) qkv = x @ c_attn_w + b (bf16 out, 256^2 dbuf-prefetch GEMM);
    //    V-part written transposed to Vtp
    gemm256_bt_kernel<<<(M_ / 256) * (T3_ / 256), 512, 0, stream>>>(
        xb, wqkvT, c_attn_b, qkv, Vtp, 2 * NX_, M_, T3_, NX_);
    // 4) attention (R4 structure, 1024 blocks)
    attn_kernel<<<1024, 256, 0, stream>>>(qkv, Vtp, attno);
    // 5) out = attn @ c_proj_w + b  (f32 out, proven 128^2 GEMM)
    gemm_bt_kernel<<<(M_ / BM) * (NX_ / BN), 256, 0, stream>>>(
        attno, wprojT, c_proj_b, nullptr, out, M_, NX_, NX_);
}

// Round 10
// 121.317 us; speedup vs baseline: 1.6480x; 1.0656x over previous
//
#include <hip/hip_runtime.h>
#include <cstdint>

typedef unsigned short u16;
typedef unsigned int u32;
typedef float f32x4 __attribute__((ext_vector_type(4)));
typedef __bf16 bf16x8 __attribute__((ext_vector_type(8)));
typedef __bf16 bf16x4 __attribute__((ext_vector_type(4)));
typedef u16 u16x8 __attribute__((ext_vector_type(8)));

#define B_ 2
#define S_ 2048
#define NX_ 1024
#define NH_ 16
#define HD_ 64
#define T3_ 3072
#define M_ 4096          // B_*S_ tokens
#define SCL 0.18033688011112042f   // 0.125 * log2(e)

__device__ __forceinline__ u16 bfbits(float f) {
    __bf16 h = (__bf16)f;            // native cvt (RNE), pairs to v_cvt_pk_bf16_f32
    return __builtin_bit_cast(u16, h);
}

__device__ __forceinline__ void gload_lds16(const void* g, void* l) {
    auto gp = reinterpret_cast<const __attribute__((address_space(1))) u32*>(
        reinterpret_cast<uintptr_t>(g));
    auto lp = reinterpret_cast<__attribute__((address_space(3))) u32*>(
        reinterpret_cast<uintptr_t>(l));
    __builtin_amdgcn_global_load_lds(gp, lp, 16, 0, 0);
}

// ---------------- convert f32 -> bf16, vectorized ----------------
__global__ __launch_bounds__(256) void cvt_bf16_kernel(const float* __restrict__ X,
                                                       u16* __restrict__ Y) {
    int i = (blockIdx.x * 256 + threadIdx.x) * 4;
    float4 v = *reinterpret_cast<const float4*>(X + i);
    bf16x4 o;
    o[0] = (__bf16)v.x; o[1] = (__bf16)v.y; o[2] = (__bf16)v.z; o[3] = (__bf16)v.w;
    *reinterpret_cast<bf16x4*>(Y + i) = o;
}

// ---------------- transpose + convert: W[K][N] f32 -> WT[N][K] bf16 ----------------
__global__ __launch_bounds__(256) void transpose_cvt_kernel(const float* __restrict__ W,
                                                            u16* __restrict__ WT,
                                                            int K, int N) {
    __shared__ float tile[32][33];
    int nbx = N >> 5;
    int nb = (blockIdx.x % nbx) << 5;
    int kb = (blockIdx.x / nbx) << 5;
    int tx = threadIdx.x & 31, ty = threadIdx.x >> 5;
#pragma unroll
    for (int i = 0; i < 32; i += 8)
        tile[ty + i][tx] = W[(size_t)(kb + ty + i) * N + nb + tx];
    __syncthreads();
#pragma unroll
    for (int i = 0; i < 32; i += 8)
        WT[(size_t)(nb + ty + i) * K + kb + tx] = bfbits(tile[tx][ty + i]);
}

// ---------------- 128^2 bf16 GEMM, double-buffered prefetch + chunk-XOR swizzle ----------------
// C[M][N] = A[M][K] * Bt[N][K]^T + bias. 256 thr (4 waves 2x2), BK=64, LDS 64KB
// (2 blocks/CU). Stage(kt+1) issued BEFORE compute(kt); ONE barrier per tile —
// its vmcnt(0) drains loads issued ~350+cy earlier (amortized; attn-proven pattern).
// Swizzle: slot ck holds data chunk ck^(row&7); read slot (ks*4+lg)^(lr&7) — R9-proven
// conflict-free. If Vt!=null, columns >= vcol0 are written transposed: Vt[g][d][s].
#define BM 128
#define BN 128
#define BK 64
__global__ __launch_bounds__(256) void gemm_bt_kernel(const u16* __restrict__ A,
                                                      const u16* __restrict__ Bt,
                                                      const float* __restrict__ bias,
                                                      u16* __restrict__ Cb,
                                                      float* __restrict__ Cf,
                                                      u16* __restrict__ Vt,
                                                      int vcol0,
                                                      int M, int N, int K) {
    __shared__ u16 a_lds[2][BM * BK];
    __shared__ u16 b_lds[2][BN * BK];
    int nbn = N / BN;
    int nwg = gridDim.x;
    int orig = blockIdx.x;
    int wg = (orig & 7) * (nwg >> 3) + (orig >> 3);   // XCD-contiguous chunks
    int bm = wg / nbn, bn = wg % nbn;
    int t = threadIdx.x;
    int w = t >> 6, l = t & 63, lg = l >> 4, lr = l & 15;
    int wr = w >> 1, wc = w & 1;
    const u16* Abase = A + (size_t)bm * BM * K;
    const u16* Bbase = Bt + (size_t)bn * BN * K;

    f32x4 zero4 = {0.f, 0.f, 0.f, 0.f};
    f32x4 acc[4][4];
#pragma unroll
    for (int m = 0; m < 4; ++m)
#pragma unroll
        for (int n = 0; n < 4; ++n) acc[m][n] = zero4;

    // stage tile kt into buffer bs: linear LDS dest (wave-uniform base + lane*16B),
    // inverse-swizzled global source chunk (both-sides pattern, R9-verified).
    auto stage = [&](int kt, int bs) {
#pragma unroll
        for (int it = 0; it < 4; ++it) {
            int idx = it * 256 + t;              // 0..1023 = 128 rows x 8 chunks
            int row = idx >> 3, ck = idx & 7;
            int cds = ck ^ (row & 7);            // data chunk stored in this slot
            int ubase = (it * 256 + w * 64) * 8; // u16 units, wave-uniform
            gload_lds16(Abase + (size_t)row * K + kt * BK + cds * 8, &a_lds[bs][ubase]);
            gload_lds16(Bbase + (size_t)row * K + kt * BK + cds * 8, &b_lds[bs][ubase]);
        }
    };

    stage(0, 0);
    __syncthreads();

    int nkt = K / BK;
    for (int kt = 0; kt < nkt; ++kt) {
        int cur = kt & 1;
        if (kt + 1 < nkt) stage(kt + 1, cur ^ 1);   // prefetch into other buffer

#pragma unroll
        for (int ks = 0; ks < 2; ++ks) {
            int ck = (ks * 4 + lg) ^ (lr & 7);      // row&7 == lr&7 for all fragment rows
            bf16x8 af[4], bf[4];
#pragma unroll
            for (int m = 0; m < 4; ++m)
                af[m] = *reinterpret_cast<const bf16x8*>(
                    &a_lds[cur][(wr * 64 + m * 16 + lr) * BK + ck * 8]);
#pragma unroll
            for (int n = 0; n < 4; ++n)
                bf[n] = *reinterpret_cast<const bf16x8*>(
                    &b_lds[cur][(wc * 64 + n * 16 + lr) * BK + ck * 8]);
            __builtin_amdgcn_s_setprio(1);
#pragma unroll
            for (int m = 0; m < 4; ++m)
#pragma unroll
                for (int n = 0; n < 4; ++n)
                    acc[m][n] = __builtin_amdgcn_mfma_f32_16x16x32_bf16(
                        af[m], bf[n], acc[m][n], 0, 0, 0);
            __builtin_amdgcn_s_setprio(0);
        }
        __syncthreads();   // one barrier/tile: drains prefetch (amortized) +
                           // all waves done reading buf[cur] before overwrite
    }

#pragma unroll
    for (int n = 0; n < 4; ++n) {
        int col0 = bn * BN + wc * 64 + n * 16;
        int col = col0 + lr;
        float bv = bias[col];
        bool isv = (Vt != nullptr) && (col0 >= vcol0);
#pragma unroll
        for (int m = 0; m < 4; ++m) {
            int row0 = bm * BM + wr * 64 + m * 16 + lg * 4;
            if (isv) {
                int nv = col - vcol0, hh = nv >> 6, dd = nv & 63;
                int bb = row0 >> 11, ss = row0 & 2047;
                bf16x4 pk;
#pragma unroll
                for (int r = 0; r < 4; ++r) pk[r] = (__bf16)(acc[m][n][r] + bv);
                *reinterpret_cast<bf16x4*>(
                    Vt + (((size_t)(bb * 16 + hh) * 64 + dd) << 11) + ss) = pk;
            } else {
#pragma unroll
                for (int r = 0; r < 4; ++r) {
                    float v = acc[m][n][r] + bv;
                    if (Cf) Cf[(size_t)(row0 + r) * N + col] = v;
                    else    Cb[(size_t)(row0 + r) * N + col] = bfbits(v);
                }
            }
        }
    }
}

// ---------------- flash attention (R4, proven 57 us): swapped-QK^T 16x16 ----------------
// One q-tile (64 rows) per block, 1024 blocks, balanced qt map, single barrier/tile.
__global__ __launch_bounds__(256) void attn_kernel(const u16* __restrict__ qkv,
                                                   const u16* __restrict__ Vt,
                                                   u16* __restrict__ outa) {
    __shared__ u16 k_lds[2][4096];   // [k 64][d 64], chunk16-swizzled ^ (row&7)
    __shared__ u16 v_lds[2][4096];   // [d 64][k 64], chunk16-swizzled ^ (row&7)
    __shared__ u16 p_lds[4096];      // [q 64][k 64], chunk16-swizzled ^ (row&7)

    int bid = blockIdx.x;
    int g = bid & 31;                // same g -> same XCD (stride 32 ≡ 0 mod 8)
    int j = bid >> 5;                // 0..31
    int j0 = j & 7, kk = j >> 3;
    int qt = (kk == 0) ? j0 : (kk == 1) ? (31 - j0) : (kk == 2) ? (8 + j0) : (23 - j0);
    int b = g >> 4, h = g & 15;
    int t = threadIdx.x, w = t >> 6, l = t & 63, lg = l >> 4, lr = l & 15;
    const u16* base = qkv + (size_t)b * S_ * T3_;
    const u16* vbase = Vt + (size_t)g * 64 * S_;
    int prow = w * 16 + lr;          // local P row (wave-private slab)
    int srow = w * 8 + (l >> 3);     // staging row (it adds 32)
    int qb = qt * 64;
    int qrow = qb + w * 16 + lr;     // this lane's q (column of S^T)

    auto stage = [&](int kt2, int bs) {
        int kb2 = kt2 * 64;
#pragma unroll
        for (int it = 0; it < 2; ++it) {
            int row = it * 32 + srow;
            int ckg = (l & 7) ^ (row & 7);       // pre-swizzled global chunk
            gload_lds16(base + (size_t)(kb2 + row) * T3_ + NX_ + h * 64 + ckg * 8,
                        &k_lds[bs][(it * 32 + w * 8) * 64]);
            gload_lds16(vbase + (size_t)row * S_ + kb2 + ckg * 8,
                        &v_lds[bs][(it * 32 + w * 8) * 64]);
        }
    };

    f32x4 zero4 = {0.f, 0.f, 0.f, 0.f};

    bf16x8 qf[2];
#pragma unroll
    for (int ks = 0; ks < 2; ++ks)
        qf[ks] = *reinterpret_cast<const bf16x8*>(
            base + (size_t)qrow * T3_ + h * 64 + ks * 32 + lg * 8);

    f32x4 oacc[4];
#pragma unroll
    for (int dc = 0; dc < 4; ++dc) oacc[dc] = zero4;
    float mrun = -1e30f, lrun = 0.f;
    int nkt = qt + 1;

    stage(0, 0);
    __syncthreads();

    for (int kt = 0; kt < nkt; ++kt) {
        int cur = kt & 1;
        if (kt + 1 < nkt) stage(kt + 1, cur ^ 1);   // issue early; drains at end barrier

        // S^T = K Q^T : lane holds S[k = kn*16+lg*4+r][q = qrow]
        f32x4 sacc[4];
#pragma unroll
        for (int kn = 0; kn < 4; ++kn) sacc[kn] = zero4;
        __builtin_amdgcn_s_setprio(1);
#pragma unroll
        for (int ks = 0; ks < 2; ++ks) {
#pragma unroll
            for (int kn = 0; kn < 4; ++kn) {
                bf16x8 kf = *reinterpret_cast<const bf16x8*>(
                    &k_lds[cur][(kn * 16 + lr) * 64 + (((ks * 4 + lg) ^ (lr & 7)) * 8)]);
                sacc[kn] = __builtin_amdgcn_mfma_f32_16x16x32_bf16(
                    kf, qf[ks], sacc[kn], 0, 0, 0);
            }
        }
        __builtin_amdgcn_s_setprio(0);

        if (kt == qt) {   // diagonal tile: causal mask (k_local > q_local)
            int qloc = w * 16 + lr;
#pragma unroll
            for (int kn = 0; kn < 4; ++kn)
#pragma unroll
                for (int r = 0; r < 4; ++r)
                    if (kn * 16 + lg * 4 + r > qloc) sacc[kn][r] = -1e30f;
        }

        // in-register online softmax (16 in-lane + 2 shfl across lg groups)
        float mx = -1e30f;
#pragma unroll
        for (int kn = 0; kn < 4; ++kn) {
            float a0 = fmaxf(sacc[kn][0], sacc[kn][1]);
            float a1 = fmaxf(sacc[kn][2], sacc[kn][3]);
            mx = fmaxf(mx, fmaxf(a0, a1));
        }
        mx = fmaxf(mx, __shfl_xor(mx, 16));
        mx = fmaxf(mx, __shfl_xor(mx, 32));

        bool noresc = __all(mx <= mrun + 8.0f);   // defer-max: P bounded by 2^(8*SCL)=2.7
        float mnew = noresc ? mrun : fmaxf(mrun, mx);

        float rs = 0.f;
#pragma unroll
        for (int kn = 0; kn < 4; ++kn)
#pragma unroll
            for (int r = 0; r < 4; ++r) {
                float pv = exp2f((sacc[kn][r] - mnew) * SCL);
                sacc[kn][r] = pv;
                rs += pv;
            }
        rs += __shfl_xor(rs, 16);
        rs += __shfl_xor(rs, 32);

        if (noresc) {
            lrun += rs;
        } else {
            float fsc = exp2f((mrun - mnew) * SCL);
            mrun = mnew;
            lrun = lrun * fsc + rs;
            float f0 = __shfl(fsc, lg * 4 + 0);
            float f1 = __shfl(fsc, lg * 4 + 1);
            float f2 = __shfl(fsc, lg * 4 + 2);
            float f3 = __shfl(fsc, lg * 4 + 3);
#pragma unroll
            for (int dc = 0; dc < 4; ++dc) {
                oacc[dc][0] *= f0; oacc[dc][1] *= f1;
                oacc[dc][2] *= f2; oacc[dc][3] *= f3;
            }
        }

        // P -> LDS, packed 8B writes, swizzled (wave-private slab: no barrier needed)
#pragma unroll
        for (int kn = 0; kn < 4; ++kn) {
            bf16x4 pb;
            pb[0] = (__bf16)sacc[kn][0]; pb[1] = (__bf16)sacc[kn][1];
            pb[2] = (__bf16)sacc[kn][2]; pb[3] = (__bf16)sacc[kn][3];
            int byteoff = prow * 128 + (((2 * kn + (lg >> 1)) ^ (prow & 7)) * 16) + (lg & 1) * 8;
            *reinterpret_cast<bf16x4*>(reinterpret_cast<char*>(p_lds) + byteoff) = pb;
        }

        // O += P V  (A = P rows from LDS, B = Vt rows)
        __builtin_amdgcn_s_setprio(1);
#pragma unroll
        for (int ks = 0; ks < 2; ++ks) {
            bf16x8 pf = *reinterpret_cast<const bf16x8*>(
                reinterpret_cast<char*>(p_lds) + prow * 128 + (((ks * 4 + lg) ^ (prow & 7)) * 16));
#pragma unroll
            for (int dc = 0; dc < 4; ++dc) {
                bf16x8 vf = *reinterpret_cast<const bf16x8*>(
                    &v_lds[cur][(dc * 16 + lr) * 64 + (((ks * 4 + lg) ^ (lr & 7)) * 8)]);
                oacc[dc] = __builtin_amdgcn_mfma_f32_16x16x32_bf16(
                    pf, vf, oacc[dc], 0, 0, 0);
            }
        }
        __builtin_amdgcn_s_setprio(0);
        __syncthreads();   // single barrier/tile: k/v_lds[cur] reads done before reuse
    }

    // epilogue: O /= l ; store bf16 [token][h*64+d]
    float inv = 1.f / lrun;
    float i0 = __shfl(inv, lg * 4 + 0);
    float i1 = __shfl(inv, lg * 4 + 1);
    float i2 = __shfl(inv, lg * 4 + 2);
    float i3 = __shfl(inv, lg * 4 + 3);
    u16* ob = outa + (size_t)b * S_ * NX_;
#pragma unroll
    for (int r = 0; r < 4; ++r) {
        float ir = (r == 0) ? i0 : (r == 1) ? i1 : (r == 2) ? i2 : i3;
        int row = qb + w * 16 + lg * 4 + r;
#pragma unroll
        for (int dc = 0; dc < 4; ++dc)
            ob[(size_t)row * NX_ + h * 64 + dc * 16 + lr] = bfbits(oacc[dc][r] * ir);
    }
}

extern "C" void kernel_launch(void* const* d_in, const int* in_sizes, int n_in,
                              void* d_out, int out_size, void* d_ws, size_t ws_size,
                              hipStream_t stream) {
    const float* x        = (const float*)d_in[0];
    const float* c_attn_w = (const float*)d_in[1];
    const float* c_attn_b = (const float*)d_in[2];
    const float* c_proj_w = (const float*)d_in[3];
    const float* c_proj_b = (const float*)d_in[4];
    float* out = (float*)d_out;

    u16* xb     = (u16*)d_ws;                         // [4096][1024] bf16  (8 MB)
    u16* wqkvT  = xb + (size_t)M_ * NX_;              // [3072][1024] bf16  (6 MB)
    u16* wprojT = wqkvT + (size_t)T3_ * NX_;          // [1024][1024] bf16  (2 MB)
    u16* qkv    = wprojT + (size_t)NX_ * NX_;         // [4096][3072] bf16  (24 MB; V part unused)
    u16* attno  = xb;                                 // reuse xb after GEMM1 (8 MB)
    u16* Vtp    = (u16*)d_out;                        // scratch: Vt 8 MB inside 16 MB out;
                                                      // fully overwritten by GEMM2 at the end

    // 1) x -> bf16
    cvt_bf16_kernel<<<(M_ * NX_) / 1024, 256, 0, stream>>>(x, xb);
    // 2) weights -> transposed bf16
    transpose_cvt_kernel<<<(T3_ / 32) * (NX_ / 32), 256, 0, stream>>>(c_attn_w, wqkvT, NX_, T3_);
    transpose_cvt_kernel<<<(NX_ / 32) * (NX_ / 32), 256, 0, stream>>>(c_proj_w, wprojT, NX_, NX_);
    // 3) qkv = x @ c_attn_w + b (bf16 out, dbuf+swizzle GEMM); V-part -> Vtp transposed
    gemm_bt_kernel<<<(M_ / BM) * (T3_ / BN), 256, 0, stream>>>(
        xb, wqkvT, c_attn_b, qkv, nullptr, Vtp, 2 * NX_, M_, T3_, NX_);
    // 4) attention (R4 structure, 1024 blocks)
    attn_kernel<<<1024, 256, 0, stream>>>(qkv, Vtp, attno);
    // 5) out = attn @ c_proj_w + b  (f32 out, dbuf+swizzle GEMM)
    gemm_bt_kernel<<<(M_ / BM) * (NX_ / BN), 256, 0, stream>>>(
        attno, wprojT, c_proj_b, nullptr, out, nullptr, 0, M_, NX_, NX_);
}